// Round 2
// baseline (169.856 us; speedup 1.0000x reference)
//
#include <hip/hip_runtime.h>

// loss = mean over all elements of (sigmoid(x) - t)^2 * ((1-t) + (x<=0 ? 1 : 0))
// distance_transform(m) == 1 - m for binary m (center tap of the 3x3 ones conv
// guarantees iteration 1 returns `inverted`; iteration 2 breaks). dt^2 = 1-t
// since t in {0,1}; preds = (sigmoid(x)>0.5) = (x>0).
//
// Single fused kernel: grid-stride float4 streaming loads, block reduce,
// per-block partial -> ws, last-block-done reduces partials and writes mean.
// ws layout: [0..3] counter (zeroed by a 4B memset node), [64..] partials.

typedef float v4f __attribute__((ext_vector_type(4)));

#define NBLOCKS 2048
#define NTHREADS 256

__device__ __forceinline__ float loss_term(float x, float t) {
    float p = 1.0f / (1.0f + __expf(-x));
    float d = p - t;
    float w = (1.0f - t) + (x > 0.0f ? 0.0f : 1.0f);
    return d * d * w;
}

// Block reduce: returns total to thread 0.
__device__ __forceinline__ float block_reduce(float v, float* smem) {
    #pragma unroll
    for (int off = 32; off > 0; off >>= 1)
        v += __shfl_down(v, off, 64);
    const int lane = threadIdx.x & 63;
    const int wave = threadIdx.x >> 6;
    if (lane == 0) smem[wave] = v;
    __syncthreads();
    float s = 0.0f;
    if (threadIdx.x == 0) {
        #pragma unroll
        for (int w = 0; w < NTHREADS / 64; ++w) s += smem[w];
    }
    return s;
}

__global__ __launch_bounds__(NTHREADS) void hausdorff_fused(
        const float* __restrict__ logits,
        const float* __restrict__ targets,
        float* __restrict__ out,
        unsigned int* __restrict__ counter,   // ws[0], zeroed by memset node
        float* __restrict__ partial,          // ws + 64 floats
        int n, float inv_n) {
    __shared__ float smem[NTHREADS / 64];

    const int tid    = blockIdx.x * blockDim.x + threadIdx.x;
    const int stride = gridDim.x * blockDim.x;
    const int n4     = n >> 2;

    const v4f* __restrict__ x4 = (const v4f*)logits;
    const v4f* __restrict__ t4 = (const v4f*)targets;

    float acc = 0.0f;
    for (int i = tid; i < n4; i += stride) {
        v4f x = __builtin_nontemporal_load(&x4[i]);
        v4f t = __builtin_nontemporal_load(&t4[i]);
        acc += loss_term(x.x, t.x);
        acc += loss_term(x.y, t.y);
        acc += loss_term(x.z, t.z);
        acc += loss_term(x.w, t.w);
    }
    // tail (not hit for n = 8M with this grid, kept for generality)
    for (int i = (n4 << 2) + tid; i < n; i += stride)
        acc += loss_term(logits[i], targets[i]);

    float s = block_reduce(acc, smem);

    __shared__ bool is_last;
    if (threadIdx.x == 0) {
        partial[blockIdx.x] = s;
        __threadfence();  // make partial visible device-wide before counting in
        unsigned int old = atomicAdd(counter, 1u);
        is_last = (old == gridDim.x - 1);
    }
    __syncthreads();

    if (is_last) {
        // all other blocks' partials are visible (fence before their counter add)
        double a = 0.0;
        for (int i = threadIdx.x; i < gridDim.x; i += blockDim.x)
            a += (double)partial[i];
        __shared__ double dsm[NTHREADS];
        dsm[threadIdx.x] = a;
        __syncthreads();
        for (int half = NTHREADS >> 1; half > 0; half >>= 1) {
            if (threadIdx.x < half) dsm[threadIdx.x] += dsm[threadIdx.x + half];
            __syncthreads();
        }
        if (threadIdx.x == 0) out[0] = (float)(dsm[0] * (double)inv_n);
    }
}

extern "C" void kernel_launch(void* const* d_in, const int* in_sizes, int n_in,
                              void* d_out, int out_size, void* d_ws, size_t ws_size,
                              hipStream_t stream) {
    const float* logits  = (const float*)d_in[0];
    const float* targets = (const float*)d_in[1];
    float* out = (float*)d_out;

    unsigned int* counter = (unsigned int*)d_ws;
    float* partial = (float*)d_ws + 64;  // 256B offset keeps partials cacheline-clean

    const int n = in_sizes[0];  // 8*1024*1024

    hipMemsetAsync(counter, 0, sizeof(unsigned int), stream);  // tiny memset node
    hausdorff_fused<<<NBLOCKS, NTHREADS, 0, stream>>>(
        logits, targets, out, counter, partial, n, 1.0f / (float)n);
}

// Round 3
// 137.620 us; speedup vs baseline: 1.2342x; 1.2342x over previous
//
#include <hip/hip_runtime.h>

// loss = mean over all elements of (sigmoid(x) - t)^2 * ((1-t) + (x<=0 ? 1 : 0))
// distance_transform(m) == 1 - m for binary m (center tap of the 3x3 ones conv
// guarantees iteration 1 returns `inverted`; iteration 2 breaks). dt^2 = 1-t
// since t in {0,1}; preds = (sigmoid(x)>0.5) = (x>0).
//
// Single kernel: grid-stride float4 loads (cached — inputs are L3-warm from the
// harness restore), block reduce, one device-scope float atomicAdd per block
// into d_out (zeroed by a 4B memset node).
//
// LESSON (round 2): __threadfence() per block = per-XCD L2 wb+inv x 2048 -> 80us
// of idle-pipe stall. Never use device fences in a hot path on CDNA; the plain
// global atomicAdd RMW is already device-coherent without flushing L2.

typedef float v4f __attribute__((ext_vector_type(4)));

#define NTHREADS 256
#define NBLOCKS 4096

__device__ __forceinline__ float loss_term(float x, float t) {
    float p = 1.0f / (1.0f + __expf(-x));
    float d = p - t;
    float w = (1.0f - t) + (x > 0.0f ? 0.0f : 1.0f);
    return d * d * w;
}

__global__ __launch_bounds__(NTHREADS) void hausdorff_kernel(
        const float* __restrict__ logits,
        const float* __restrict__ targets,
        float* __restrict__ out,
        int n, float inv_n) {
    const int tid    = blockIdx.x * blockDim.x + threadIdx.x;
    const int stride = gridDim.x * blockDim.x;
    const int n4     = n >> 2;

    const v4f* __restrict__ x4 = (const v4f*)logits;
    const v4f* __restrict__ t4 = (const v4f*)targets;

    float acc = 0.0f;
    for (int i = tid; i < n4; i += stride) {
        v4f x = x4[i];
        v4f t = t4[i];
        acc += loss_term(x.x, t.x);
        acc += loss_term(x.y, t.y);
        acc += loss_term(x.z, t.z);
        acc += loss_term(x.w, t.w);
    }
    // tail (not hit for n = 8M, kept for generality)
    for (int i = (n4 << 2) + tid; i < n; i += stride)
        acc += loss_term(logits[i], targets[i]);

    // wave64 reduce
    #pragma unroll
    for (int off = 32; off > 0; off >>= 1)
        acc += __shfl_down(acc, off, 64);

    __shared__ float smem[NTHREADS / 64];
    const int lane = threadIdx.x & 63;
    const int wave = threadIdx.x >> 6;
    if (lane == 0) smem[wave] = acc;
    __syncthreads();

    if (threadIdx.x == 0) {
        float s = 0.0f;
        #pragma unroll
        for (int w = 0; w < NTHREADS / 64; ++w) s += smem[w];
        atomicAdd(out, s * inv_n);   // device-scope by default; no L2 flush
    }
}

extern "C" void kernel_launch(void* const* d_in, const int* in_sizes, int n_in,
                              void* d_out, int out_size, void* d_ws, size_t ws_size,
                              hipStream_t stream) {
    const float* logits  = (const float*)d_in[0];
    const float* targets = (const float*)d_in[1];
    float* out = (float*)d_out;

    const int n = in_sizes[0];  // 8*1024*1024

    hipMemsetAsync(out, 0, sizeof(float), stream);  // d_out is poisoned 0xAA
    hausdorff_kernel<<<NBLOCKS, NTHREADS, 0, stream>>>(
        logits, targets, out, n, 1.0f / (float)n);
}

// Round 4
// 133.997 us; speedup vs baseline: 1.2676x; 1.0270x over previous
//
#include <hip/hip_runtime.h>

// loss = mean over all elements of (sigmoid(x) - t)^2 * ((1-t) + (x<=0 ? 1 : 0))
// distance_transform(m) == 1 - m for binary m (center tap of the 3x3 ones conv
// guarantees iteration 1 returns `inverted`; iteration 2 breaks). dt^2 = 1-t
// since t in {0,1}; preds = (sigmoid(x)>0.5) = (x>0).
//
// LESSONS:
//  R2: __threadfence() per block = per-XCD L2 wb+inv -> ~80us idle stall. Never.
//  R3: 4096 same-address atomicAdd serialize at ~11.5ns each at the coherence
//      point AND backpressure block retirement -> +47us. Fan out atomics.
//
// Design: single streaming kernel (float4 grid-stride, block reduce). Each
// block atomicAdds its partial into one of 64 accumulators spread 256B apart
// (contention 64-deep, parallel across L2 channels). A wave-local
// s_waitcnt vmcnt(0) (cheap - no cache flush) orders accum-add before
// counter-add; the last block reads the 64 accums via atomicAdd(p, 0.0f)
// (RMW at the coherence point - immune to stale L1/L2) and writes the mean.
// One 16.6KB memset node zeroes counter+accums (d_ws is poisoned 0xAA).

typedef float v4f __attribute__((ext_vector_type(4)));

#define NTHREADS 256
#define NBLOCKS  4096
#define NACCUM   64
#define ACCUM_STRIDE 64   // floats: 256B between accumulators

__device__ __forceinline__ float loss_term(float x, float t) {
    float p = 1.0f / (1.0f + __expf(-x));
    float d = p - t;
    float w = (1.0f - t) + (x > 0.0f ? 0.0f : 1.0f);
    return d * d * w;
}

__global__ __launch_bounds__(NTHREADS) void hausdorff_fused(
        const float* __restrict__ logits,
        const float* __restrict__ targets,
        float* __restrict__ out,
        unsigned int* __restrict__ counter,  // ws[0]
        float* __restrict__ accum,           // ws + 64 floats, 64 slots x 256B
        int n, float inv_n) {
    const int tid    = blockIdx.x * blockDim.x + threadIdx.x;
    const int stride = gridDim.x * blockDim.x;
    const int n4     = n >> 2;

    const v4f* __restrict__ x4 = (const v4f*)logits;
    const v4f* __restrict__ t4 = (const v4f*)targets;

    float acc = 0.0f;
    for (int i = tid; i < n4; i += stride) {
        v4f x = x4[i];
        v4f t = t4[i];
        acc += loss_term(x.x, t.x);
        acc += loss_term(x.y, t.y);
        acc += loss_term(x.z, t.z);
        acc += loss_term(x.w, t.w);
    }
    for (int i = (n4 << 2) + tid; i < n; i += stride)   // tail: empty for n=8M
        acc += loss_term(logits[i], targets[i]);

    // wave64 butterfly
    #pragma unroll
    for (int off = 32; off > 0; off >>= 1)
        acc += __shfl_down(acc, off, 64);

    __shared__ float smem[NTHREADS / 64];
    __shared__ bool is_last;
    const int lane = threadIdx.x & 63;
    const int wave = threadIdx.x >> 6;
    if (lane == 0) smem[wave] = acc;
    __syncthreads();

    if (threadIdx.x == 0) {
        float s = 0.0f;
        #pragma unroll
        for (int w = 0; w < NTHREADS / 64; ++w) s += smem[w];
        atomicAdd(&accum[(blockIdx.x & (NACCUM - 1)) * ACCUM_STRIDE], s);
        // Order accum-add before counter-add. Wave-local drain only; NOT a
        // cache flush (cf. R2 threadfence disaster).
        asm volatile("s_waitcnt vmcnt(0)" ::: "memory");
        unsigned int old = atomicAdd(counter, 1u);
        is_last = (old == (unsigned int)(gridDim.x - 1));
    }
    __syncthreads();

    if (is_last && threadIdx.x < NACCUM) {
        // Atomic RMW read executes at the coherence point: sees every accum-add
        // that preceded the counter-adds we observed.
        float v = atomicAdd(&accum[threadIdx.x * ACCUM_STRIDE], 0.0f);
        #pragma unroll
        for (int off = 32; off > 0; off >>= 1)
            v += __shfl_down(v, off, 64);
        if (threadIdx.x == 0) out[0] = v * inv_n;
    }
}

extern "C" void kernel_launch(void* const* d_in, const int* in_sizes, int n_in,
                              void* d_out, int out_size, void* d_ws, size_t ws_size,
                              hipStream_t stream) {
    const float* logits  = (const float*)d_in[0];
    const float* targets = (const float*)d_in[1];
    float* out = (float*)d_out;

    unsigned int* counter = (unsigned int*)d_ws;
    float* accum = (float*)d_ws + 64;

    const int n = in_sizes[0];  // 8*1024*1024

    // zero counter + 64 spread accumulators (ws is poisoned 0xAA each launch)
    hipMemsetAsync(d_ws, 0, (64 + NACCUM * ACCUM_STRIDE) * sizeof(float), stream);
    hausdorff_fused<<<NBLOCKS, NTHREADS, 0, stream>>>(
        logits, targets, out, counter, accum, n, 1.0f / (float)n);
}

// Round 5
// 94.104 us; speedup vs baseline: 1.8050x; 1.4239x over previous
//
#include <hip/hip_runtime.h>

// loss = mean over all elements of (sigmoid(x) - t)^2 * ((1-t) + (x<=0 ? 1 : 0))
// distance_transform(m) == 1 - m for binary m (center tap of the 3x3 ones conv
// guarantees iteration 1 returns `inverted`; iteration 2 breaks). dt^2 = 1-t
// since t in {0,1}; preds = (sigmoid(x)>0.5) = (x>0).
//
// LESSONS (counter-verified):
//  R2: __threadfence() per block = per-XCD L2 wb+inv -> ~80us idle-pipe stall.
//  R3/R4: N-deep same-address atomicAdd (result consumed) serializes at
//      ~11.5ns each and blocks retirement: 4096 deep -> +45us. The fan-out
//      accum atomics were fine; the single shared counter was not.
//  => Two plain kernels with NO atomics/fences is the fastest structure here:
//     both kernels measured ~18us combined (R1) vs 57-60us fused-with-atomics.
//
// kernel1: 2048 blocks x 256 thr (8 blk/CU = 32 waves/CU, one dispatch round),
//   grid-stride float4, wave+LDS reduce, plain store of one partial per block.
// kernel2: one block reduces 2048 partials (double accum) and writes the mean.
// Visibility via kernel boundary; no memset nodes needed (all ws slots written
// by kernel1 before kernel2 reads; out written unconditionally).

typedef float v4f __attribute__((ext_vector_type(4)));

#define NTHREADS 256
#define NBLOCKS  2048

__device__ __forceinline__ float loss_term(float x, float t) {
    float p = 1.0f / (1.0f + __expf(-x));
    float d = p - t;
    float w = (1.0f - t) + (x > 0.0f ? 0.0f : 1.0f);
    return d * d * w;
}

__global__ __launch_bounds__(NTHREADS) void hausdorff_partial(
        const float* __restrict__ logits,
        const float* __restrict__ targets,
        float* __restrict__ partial,
        int n) {
    const int tid    = blockIdx.x * blockDim.x + threadIdx.x;
    const int stride = gridDim.x * blockDim.x;
    const int n4     = n >> 2;

    const v4f* __restrict__ x4 = (const v4f*)logits;
    const v4f* __restrict__ t4 = (const v4f*)targets;

    float acc = 0.0f;
    for (int i = tid; i < n4; i += stride) {
        v4f x = x4[i];
        v4f t = t4[i];
        acc += loss_term(x.x, t.x);
        acc += loss_term(x.y, t.y);
        acc += loss_term(x.z, t.z);
        acc += loss_term(x.w, t.w);
    }
    for (int i = (n4 << 2) + tid; i < n; i += stride)   // tail: empty for n=8M
        acc += loss_term(logits[i], targets[i]);

    #pragma unroll
    for (int off = 32; off > 0; off >>= 1)
        acc += __shfl_down(acc, off, 64);

    __shared__ float smem[NTHREADS / 64];
    const int lane = threadIdx.x & 63;
    const int wave = threadIdx.x >> 6;
    if (lane == 0) smem[wave] = acc;
    __syncthreads();

    if (threadIdx.x == 0) {
        float s = 0.0f;
        #pragma unroll
        for (int w = 0; w < NTHREADS / 64; ++w) s += smem[w];
        partial[blockIdx.x] = s;    // plain store — no atomic, no fence
    }
}

__global__ __launch_bounds__(NTHREADS) void hausdorff_final(
        const float* __restrict__ partial,
        float* __restrict__ out,
        int nblocks, double inv_n) {
    double acc = 0.0;
    for (int i = threadIdx.x; i < nblocks; i += blockDim.x)
        acc += (double)partial[i];

    __shared__ double smem[NTHREADS];
    smem[threadIdx.x] = acc;
    __syncthreads();
    #pragma unroll
    for (int half = NTHREADS >> 1; half > 0; half >>= 1) {
        if (threadIdx.x < half) smem[threadIdx.x] += smem[threadIdx.x + half];
        __syncthreads();
    }
    if (threadIdx.x == 0) out[0] = (float)(smem[0] * inv_n);
}

extern "C" void kernel_launch(void* const* d_in, const int* in_sizes, int n_in,
                              void* d_out, int out_size, void* d_ws, size_t ws_size,
                              hipStream_t stream) {
    const float* logits  = (const float*)d_in[0];
    const float* targets = (const float*)d_in[1];
    float* out = (float*)d_out;
    float* partial = (float*)d_ws;

    const int n = in_sizes[0];  // 8*1024*1024

    hausdorff_partial<<<NBLOCKS, NTHREADS, 0, stream>>>(logits, targets, partial, n);
    hausdorff_final<<<1, NTHREADS, 0, stream>>>(partial, out, NBLOCKS, 1.0 / (double)n);
}